// Round 1
// baseline (402.814 us; speedup 1.0000x reference)
//
#include <hip/hip_runtime.h>

#define N_NODES 50000
#define N_EDGES 800000
#define IN_CH 128
#define OUT_CH 64
#define HEADS 4
#define HC 256  // HEADS*OUT_CH
#define NEG_SLOPE 0.2f

// ---------------- workspace layout (bytes) ----------------
// h:       50000*256*4 = 51,200,000
// a_src:   50000*4*4   =    800,000
// a_dst:   50000*4*4   =    800,000
// counts:  50000*4     =    200,000
// offsets: 50000*4     =    200,000
// cursor:  50000*4     =    200,000
// bsums:   pad 1024
// csr:     800000*4    =  3,200,000
#define H_OFF        0UL
#define ASRC_OFF     51200000UL
#define ADST_OFF     52000000UL
#define COUNTS_OFF   52800000UL
#define OFFSETS_OFF  53000000UL
#define CURSOR_OFF   53200000UL
#define BSUMS_OFF    53400000UL
#define CSR_OFF      53401024UL
// total ≈ 56.6 MB

// ---------------- SGEMM: h = x @ W  (M=50000, K=128, N=256) ----------------
__global__ __launch_bounds__(256) void sgemm_xw(const float* __restrict__ x,
                                                const float* __restrict__ W,
                                                float* __restrict__ h) {
  __shared__ float As[32][65];  // [k][m], padded
  __shared__ float Bs[32][65];  // [k][n], padded
  const int m0 = blockIdx.x * 64;
  const int n0 = blockIdx.y * 64;
  const int tid = threadIdx.x;
  const int tm = tid >> 4;   // 0..15
  const int tn = tid & 15;   // 0..15
  float acc[4][4] = {};
  for (int k0 = 0; k0 < 128; k0 += 32) {
#pragma unroll
    for (int it = 0; it < 8; ++it) {   // A tile: 64 rows x 32 k
      int idx = it * 256 + tid;
      int m = idx >> 5, kk = idx & 31;
      int row = m0 + m;
      As[kk][m] = (row < N_NODES) ? x[row * IN_CH + k0 + kk] : 0.f;
    }
#pragma unroll
    for (int it = 0; it < 8; ++it) {   // B tile: 32 k x 64 cols
      int idx = it * 256 + tid;
      int kk = idx >> 6, nn = idx & 63;
      Bs[kk][nn] = W[(k0 + kk) * HC + n0 + nn];
    }
    __syncthreads();
#pragma unroll
    for (int k = 0; k < 32; ++k) {
      float a[4], b[4];
#pragma unroll
      for (int i = 0; i < 4; ++i) a[i] = As[k][tm * 4 + i];
#pragma unroll
      for (int j = 0; j < 4; ++j) b[j] = Bs[k][tn * 4 + j];
#pragma unroll
      for (int i = 0; i < 4; ++i)
#pragma unroll
        for (int j = 0; j < 4; ++j) acc[i][j] += a[i] * b[j];
    }
    __syncthreads();
  }
#pragma unroll
  for (int i = 0; i < 4; ++i) {
    int row = m0 + tm * 4 + i;
    if (row < N_NODES) {
      float4 v = make_float4(acc[i][0], acc[i][1], acc[i][2], acc[i][3]);
      *(float4*)(h + (size_t)row * HC + n0 + tn * 4) = v;
    }
  }
}

// ---------------- per-node attention logits ----------------
// wave per node; lane l: head = l>>4, channels 4l..4l+3 (note 4l == head*64 + (l&15)*4)
__global__ __launch_bounds__(256) void attn_logits(const float* __restrict__ h,
                                                   const float* __restrict__ att_s,
                                                   const float* __restrict__ att_d,
                                                   float* __restrict__ a_src,
                                                   float* __restrict__ a_dst) {
  const int node = blockIdx.x * 4 + (threadIdx.x >> 6);
  const int l = threadIdx.x & 63;
  float4 h4 = *(const float4*)(h + (size_t)node * HC + l * 4);
  float4 s4 = *(const float4*)(att_s + l * 4);
  float4 d4 = *(const float4*)(att_d + l * 4);
  float ps = h4.x * s4.x + h4.y * s4.y + h4.z * s4.z + h4.w * s4.w;
  float pd = h4.x * d4.x + h4.y * d4.y + h4.z * d4.z + h4.w * d4.w;
#pragma unroll
  for (int mask = 8; mask >= 1; mask >>= 1) {
    ps += __shfl_xor(ps, mask, 16);
    pd += __shfl_xor(pd, mask, 16);
  }
  if ((l & 15) == 0) {
    int hd = l >> 4;
    a_src[node * HEADS + hd] = ps;
    a_dst[node * HEADS + hd] = pd;
  }
}

// ---------------- CSR build ----------------
__global__ __launch_bounds__(256) void count_k(const int* __restrict__ dst,
                                               int* __restrict__ counts) {
  int e = blockIdx.x * 256 + threadIdx.x;
  if (e < N_EDGES) atomicAdd(&counts[dst[e]], 1);
}

__global__ __launch_bounds__(256) void scan1(const int* __restrict__ counts,
                                             int* __restrict__ offsets,
                                             int* __restrict__ bsums) {
  __shared__ int sd[256];
  const int base = blockIdx.x * 1024;
  const int t = threadIdx.x;
  int v[4];
  int tsum = 0;
#pragma unroll
  for (int k = 0; k < 4; ++k) {
    int i = base + t * 4 + k;
    v[k] = (i < N_NODES) ? counts[i] : 0;
    tsum += v[k];
  }
  sd[t] = tsum;
  __syncthreads();
  for (int off = 1; off < 256; off <<= 1) {
    int xval = (t >= off) ? sd[t - off] : 0;
    __syncthreads();
    sd[t] += xval;
    __syncthreads();
  }
  int excl = sd[t] - tsum;
  int run = excl;
#pragma unroll
  for (int k = 0; k < 4; ++k) {
    int i = base + t * 4 + k;
    if (i < N_NODES) offsets[i] = run;
    run += v[k];
  }
  if (t == 255) bsums[blockIdx.x] = sd[255];
}

__global__ void scan2(int* __restrict__ bsums, int nb) {
  if (threadIdx.x == 0 && blockIdx.x == 0) {
    int run = 0;
    for (int b = 0; b < nb; ++b) {
      int t = bsums[b];
      bsums[b] = run;
      run += t;
    }
  }
}

__global__ __launch_bounds__(256) void scan3(int* __restrict__ offsets,
                                             const int* __restrict__ bsums,
                                             int* __restrict__ cursor) {
  const int base = blockIdx.x * 1024;
  const int t = threadIdx.x;
  int add = bsums[blockIdx.x];
#pragma unroll
  for (int k = 0; k < 4; ++k) {
    int i = base + t * 4 + k;
    if (i < N_NODES) {
      int o = offsets[i] + add;
      offsets[i] = o;
      cursor[i] = o;
    }
  }
}

__global__ __launch_bounds__(256) void scatter_k(const int* __restrict__ src,
                                                 const int* __restrict__ dst,
                                                 int* __restrict__ cursor,
                                                 int* __restrict__ csr) {
  int e = blockIdx.x * 256 + threadIdx.x;
  if (e < N_EDGES) {
    int d = dst[e];
    int pos = atomicAdd(&cursor[d], 1);
    csr[pos] = src[e];
  }
}

// ---------------- segment softmax + aggregate ----------------
// wave per node; lane l: head hd=l>>4, channels 4l..4l+3; self-loop handled in-register.
__global__ __launch_bounds__(256) void aggregate(const float* __restrict__ h,
                                                 const float* __restrict__ a_src,
                                                 const float* __restrict__ a_dst,
                                                 const int* __restrict__ counts,
                                                 const int* __restrict__ offsets,
                                                 const int* __restrict__ csr,
                                                 const float* __restrict__ bias,
                                                 float* __restrict__ out) {
  const int node = blockIdx.x * 4 + (threadIdx.x >> 6);
  const int l = threadIdx.x & 63;
  const int hd = l >> 4;
  const int sub = l & 15;
  const int deg = counts[node];
  const int start = offsets[node];
  const float adst = a_dst[node * HEADS + hd];

  // self-loop score
  float e_self = a_src[node * HEADS + hd] + adst;
  e_self = e_self > 0.f ? e_self : NEG_SLOPE * e_self;

  // pass 1: per-head max (16 lanes of the head group stride over edges)
  float m = e_self;
  for (int j = sub; j < deg; j += 16) {
    int s = csr[start + j];
    float e = a_src[s * HEADS + hd] + adst;
    e = e > 0.f ? e : NEG_SLOPE * e;
    m = fmaxf(m, e);
  }
#pragma unroll
  for (int mask = 8; mask >= 1; mask >>= 1) m = fmaxf(m, __shfl_xor(m, mask, 16));

  // pass 2: weighted accumulation
  float ex_self = __expf(e_self - m);
  float denom = ex_self;
  float4 hv = *(const float4*)(h + (size_t)node * HC + l * 4);
  float4 acc = make_float4(hv.x * ex_self, hv.y * ex_self, hv.z * ex_self, hv.w * ex_self);
  for (int j = 0; j < deg; ++j) {
    int s = csr[start + j];
    float e = a_src[s * HEADS + hd] + adst;
    e = e > 0.f ? e : NEG_SLOPE * e;
    float ex = __expf(e - m);
    denom += ex;
    float4 hs = *(const float4*)(h + (size_t)s * HC + l * 4);
    acc.x += hs.x * ex;
    acc.y += hs.y * ex;
    acc.z += hs.z * ex;
    acc.w += hs.w * ex;
  }
  float inv = 1.f / (denom + 1e-16f);
  float4 b4 = *(const float4*)(bias + l * 4);
  float4 o = make_float4(acc.x * inv + b4.x, acc.y * inv + b4.y, acc.z * inv + b4.z,
                         acc.w * inv + b4.w);
  *(float4*)(out + (size_t)node * HC + l * 4) = o;
}

extern "C" void kernel_launch(void* const* d_in, const int* in_sizes, int n_in,
                              void* d_out, int out_size, void* d_ws, size_t ws_size,
                              hipStream_t stream) {
  const float* x     = (const float*)d_in[0];
  const int*   ei    = (const int*)d_in[1];
  const float* W     = (const float*)d_in[2];
  const float* att_s = (const float*)d_in[3];
  const float* att_d = (const float*)d_in[4];
  const float* bias  = (const float*)d_in[5];
  float* out = (float*)d_out;

  char* ws = (char*)d_ws;
  float* h      = (float*)(ws + H_OFF);
  float* a_src  = (float*)(ws + ASRC_OFF);
  float* a_dst  = (float*)(ws + ADST_OFF);
  int* counts   = (int*)(ws + COUNTS_OFF);
  int* offsets  = (int*)(ws + OFFSETS_OFF);
  int* cursor   = (int*)(ws + CURSOR_OFF);
  int* bsums    = (int*)(ws + BSUMS_OFF);
  int* csr      = (int*)(ws + CSR_OFF);

  const int* src = ei;             // edge_index[0]
  const int* dst = ei + N_EDGES;   // edge_index[1]

  hipMemsetAsync(counts, 0, N_NODES * sizeof(int), stream);

  sgemm_xw<<<dim3(782, 4), 256, 0, stream>>>(x, W, h);
  attn_logits<<<12500, 256, 0, stream>>>(h, att_s, att_d, a_src, a_dst);
  count_k<<<3125, 256, 0, stream>>>(dst, counts);
  scan1<<<49, 256, 0, stream>>>(counts, offsets, bsums);
  scan2<<<1, 64, 0, stream>>>(bsums, 49);
  scan3<<<49, 256, 0, stream>>>(offsets, bsums, cursor);
  scatter_k<<<3125, 256, 0, stream>>>(src, dst, cursor, csr);
  aggregate<<<12500, 256, 0, stream>>>(h, a_src, a_dst, counts, offsets, csr, bias, out);
}

// Round 2
// 375.018 us; speedup vs baseline: 1.0741x; 1.0741x over previous
//
#include <hip/hip_runtime.h>

#define N_NODES 50000
#define N_EDGES 800000
#define IN_CH 128
#define OUT_CH 64
#define HEADS 4
#define HC 256  // HEADS*OUT_CH
#define NEG_SLOPE 0.2f

// ---------------- workspace layout (bytes) ----------------
// hb (bf16): 50000*256*2 = 25,600,000
// a_src:     50000*4*4   =    800,000
// a_dst:     50000*4*4   =    800,000
// counts:    50000*4     =    200,000
// offsets:   50000*4     =    200,000
// cursor:    50000*4     =    200,000
// bsums:     pad 1024
// csr:       800000*4    =  3,200,000
#define HB_OFF       0UL
#define ASRC_OFF     25600000UL
#define ADST_OFF     26400000UL
#define COUNTS_OFF   27200000UL
#define OFFSETS_OFF  27400000UL
#define CURSOR_OFF   27600000UL
#define BSUMS_OFF    27800000UL
#define CSR_OFF      27801024UL
// total ≈ 31 MB

__device__ __forceinline__ unsigned short f2bf(float f) {
  unsigned int u = __float_as_uint(f);
  unsigned int r = (u + 0x7fffu + ((u >> 16) & 1u)) >> 16;
  return (unsigned short)r;
}
__device__ __forceinline__ float bf2f(unsigned short b) {
  return __uint_as_float(((unsigned int)b) << 16);
}

// ---------------- fused GEMM + logits ----------------
// thread = (row, head). acc[64] in VGPRs; W and att vectors are wave-uniform
// -> scalar loads feeding v_fmac v,s,v. No LDS, no barriers.
__global__ __launch_bounds__(256) void gemm_logits(const float* __restrict__ x,
                                                   const float* __restrict__ W,
                                                   const float* __restrict__ att_s,
                                                   const float* __restrict__ att_d,
                                                   unsigned short* __restrict__ hb,
                                                   float* __restrict__ a_src,
                                                   float* __restrict__ a_dst) {
  const int row = blockIdx.x * 256 + threadIdx.x;
  const int hd = blockIdx.y;          // 0..3
  const int n0 = hd * OUT_CH;         // column base within HC
  const bool valid = row < N_NODES;
  const int r = valid ? row : 0;

  float acc[64];
#pragma unroll
  for (int c = 0; c < 64; ++c) acc[c] = 0.f;

  const float* xr = x + (size_t)r * IN_CH;

  for (int k0 = 0; k0 < IN_CH; k0 += 32) {
    float xv[32];
#pragma unroll
    for (int q = 0; q < 8; ++q) {
      float4 t = *(const float4*)(xr + k0 + q * 4);
      xv[q * 4 + 0] = t.x;
      xv[q * 4 + 1] = t.y;
      xv[q * 4 + 2] = t.z;
      xv[q * 4 + 3] = t.w;
    }
#pragma unroll
    for (int kk = 0; kk < 32; ++kk) {
      const float* wrow = W + (size_t)(k0 + kk) * HC + n0;  // uniform -> s_load
#pragma unroll
      for (int c = 0; c < 64; ++c) acc[c] = fmaf(xv[kk], wrow[c], acc[c]);
    }
  }

  // fused attention logits for this (row, head)
  float as = 0.f, ad = 0.f;
#pragma unroll
  for (int c = 0; c < 64; ++c) {
    as = fmaf(acc[c], att_s[n0 + c], as);  // uniform -> s_load
    ad = fmaf(acc[c], att_d[n0 + c], ad);
  }

  if (valid) {
    a_src[row * HEADS + hd] = as;
    a_dst[row * HEADS + hd] = ad;
    unsigned short* hrow = hb + (size_t)row * HC + n0;
#pragma unroll
    for (int c = 0; c < 64; c += 8) {
      uint4 p;
      p.x = (unsigned int)f2bf(acc[c + 0]) | ((unsigned int)f2bf(acc[c + 1]) << 16);
      p.y = (unsigned int)f2bf(acc[c + 2]) | ((unsigned int)f2bf(acc[c + 3]) << 16);
      p.z = (unsigned int)f2bf(acc[c + 4]) | ((unsigned int)f2bf(acc[c + 5]) << 16);
      p.w = (unsigned int)f2bf(acc[c + 6]) | ((unsigned int)f2bf(acc[c + 7]) << 16);
      *(uint4*)(hrow + c) = p;
    }
  }
}

// ---------------- CSR build ----------------
__global__ __launch_bounds__(256) void count_k(const int* __restrict__ dst,
                                               int* __restrict__ counts) {
  int e = blockIdx.x * 256 + threadIdx.x;
  if (e < N_EDGES) atomicAdd(&counts[dst[e]], 1);
}

__global__ __launch_bounds__(256) void scan1(const int* __restrict__ counts,
                                             int* __restrict__ offsets,
                                             int* __restrict__ bsums) {
  __shared__ int sd[256];
  const int base = blockIdx.x * 1024;
  const int t = threadIdx.x;
  int v[4];
  int tsum = 0;
#pragma unroll
  for (int k = 0; k < 4; ++k) {
    int i = base + t * 4 + k;
    v[k] = (i < N_NODES) ? counts[i] : 0;
    tsum += v[k];
  }
  sd[t] = tsum;
  __syncthreads();
  for (int off = 1; off < 256; off <<= 1) {
    int xval = (t >= off) ? sd[t - off] : 0;
    __syncthreads();
    sd[t] += xval;
    __syncthreads();
  }
  int excl = sd[t] - tsum;
  int run = excl;
#pragma unroll
  for (int k = 0; k < 4; ++k) {
    int i = base + t * 4 + k;
    if (i < N_NODES) offsets[i] = run;
    run += v[k];
  }
  if (t == 255) bsums[blockIdx.x] = sd[255];
}

__global__ void scan2(int* __restrict__ bsums, int nb) {
  if (threadIdx.x == 0 && blockIdx.x == 0) {
    int run = 0;
    for (int b = 0; b < nb; ++b) {
      int t = bsums[b];
      bsums[b] = run;
      run += t;
    }
  }
}

__global__ __launch_bounds__(256) void scan3(int* __restrict__ offsets,
                                             const int* __restrict__ bsums,
                                             int* __restrict__ cursor) {
  const int base = blockIdx.x * 1024;
  const int t = threadIdx.x;
  int add = bsums[blockIdx.x];
#pragma unroll
  for (int k = 0; k < 4; ++k) {
    int i = base + t * 4 + k;
    if (i < N_NODES) {
      int o = offsets[i] + add;
      offsets[i] = o;
      cursor[i] = o;
    }
  }
}

__global__ __launch_bounds__(256) void scatter_k(const int* __restrict__ src,
                                                 const int* __restrict__ dst,
                                                 int* __restrict__ cursor,
                                                 int* __restrict__ csr) {
  int e = blockIdx.x * 256 + threadIdx.x;
  if (e < N_EDGES) {
    int d = dst[e];
    int pos = atomicAdd(&cursor[d], 1);
    csr[pos] = src[e];
  }
}

// ---------------- segment softmax + aggregate (bf16 h) ----------------
// wave per node; lane l: head hd=l>>4, channels 4l..4l+3; self-loop in-register.
__global__ __launch_bounds__(256) void aggregate(const unsigned short* __restrict__ hb,
                                                 const float* __restrict__ a_src,
                                                 const float* __restrict__ a_dst,
                                                 const int* __restrict__ counts,
                                                 const int* __restrict__ offsets,
                                                 const int* __restrict__ csr,
                                                 const float* __restrict__ bias,
                                                 float* __restrict__ out) {
  const int node = blockIdx.x * 4 + (threadIdx.x >> 6);
  const int l = threadIdx.x & 63;
  const int hd = l >> 4;
  const int sub = l & 15;
  const int deg = counts[node];
  const int start = offsets[node];
  const float adst = a_dst[node * HEADS + hd];

  float e_self = a_src[node * HEADS + hd] + adst;
  e_self = e_self > 0.f ? e_self : NEG_SLOPE * e_self;

  // pass 1: per-head max
  float m = e_self;
  for (int j = sub; j < deg; j += 16) {
    int s = csr[start + j];
    float e = a_src[s * HEADS + hd] + adst;
    e = e > 0.f ? e : NEG_SLOPE * e;
    m = fmaxf(m, e);
  }
#pragma unroll
  for (int mask = 8; mask >= 1; mask >>= 1) m = fmaxf(m, __shfl_xor(m, mask, 16));

  // pass 2: weighted accumulation
  float ex_self = __expf(e_self - m);
  float denom = ex_self;
  ushort4 hs4 = *(const ushort4*)(hb + (size_t)node * HC + l * 4);
  float4 acc = make_float4(bf2f(hs4.x) * ex_self, bf2f(hs4.y) * ex_self,
                           bf2f(hs4.z) * ex_self, bf2f(hs4.w) * ex_self);
  for (int j = 0; j < deg; ++j) {
    int s = csr[start + j];
    float e = a_src[s * HEADS + hd] + adst;
    e = e > 0.f ? e : NEG_SLOPE * e;
    float ex = __expf(e - m);
    denom += ex;
    ushort4 h4 = *(const ushort4*)(hb + (size_t)s * HC + l * 4);
    acc.x += bf2f(h4.x) * ex;
    acc.y += bf2f(h4.y) * ex;
    acc.z += bf2f(h4.z) * ex;
    acc.w += bf2f(h4.w) * ex;
  }
  float inv = 1.f / (denom + 1e-16f);
  float4 b4 = *(const float4*)(bias + l * 4);
  float4 o = make_float4(acc.x * inv + b4.x, acc.y * inv + b4.y, acc.z * inv + b4.z,
                         acc.w * inv + b4.w);
  *(float4*)(out + (size_t)node * HC + l * 4) = o;
}

extern "C" void kernel_launch(void* const* d_in, const int* in_sizes, int n_in,
                              void* d_out, int out_size, void* d_ws, size_t ws_size,
                              hipStream_t stream) {
  const float* x     = (const float*)d_in[0];
  const int*   ei    = (const int*)d_in[1];
  const float* W     = (const float*)d_in[2];
  const float* att_s = (const float*)d_in[3];
  const float* att_d = (const float*)d_in[4];
  const float* bias  = (const float*)d_in[5];
  float* out = (float*)d_out;

  char* ws = (char*)d_ws;
  unsigned short* hb = (unsigned short*)(ws + HB_OFF);
  float* a_src  = (float*)(ws + ASRC_OFF);
  float* a_dst  = (float*)(ws + ADST_OFF);
  int* counts   = (int*)(ws + COUNTS_OFF);
  int* offsets  = (int*)(ws + OFFSETS_OFF);
  int* cursor   = (int*)(ws + CURSOR_OFF);
  int* bsums    = (int*)(ws + BSUMS_OFF);
  int* csr      = (int*)(ws + CSR_OFF);

  const int* src = ei;             // edge_index[0]
  const int* dst = ei + N_EDGES;   // edge_index[1]

  hipMemsetAsync(counts, 0, N_NODES * sizeof(int), stream);

  gemm_logits<<<dim3(196, 4), 256, 0, stream>>>(x, W, att_s, att_d, hb, a_src, a_dst);
  count_k<<<3125, 256, 0, stream>>>(dst, counts);
  scan1<<<49, 256, 0, stream>>>(counts, offsets, bsums);
  scan2<<<1, 64, 0, stream>>>(bsums, 49);
  scan3<<<49, 256, 0, stream>>>(offsets, bsums, cursor);
  scatter_k<<<3125, 256, 0, stream>>>(src, dst, cursor, csr);
  aggregate<<<12500, 256, 0, stream>>>(hb, a_src, a_dst, counts, offsets, csr, bias, out);
}

// Round 3
// 272.333 us; speedup vs baseline: 1.4791x; 1.3771x over previous
//
#include <hip/hip_runtime.h>

#define N_NODES 50000
#define N_EDGES 800000
#define IN_CH 128
#define OUT_CH 64
#define HEADS 4
#define HC 256  // HEADS*OUT_CH
#define NEG_SLOPE 0.2f

// ---------------- workspace layout (bytes) ----------------
#define HB_OFF       0UL          // bf16 h: 50000*256*2 = 25,600,000
#define WSW_OFF      25600000UL   // swizzled bf16 W: 65,536
#define ASRC_OFF     25665536UL   // 800,000
#define ADST_OFF     26465536UL   // 800,000
#define COUNTS_OFF   27265536UL   // 200,000
#define OFFSETS_OFF  27465536UL   // 200,000
#define CURSOR_OFF   27665536UL   // 200,000
#define BSUMS_OFF    27865536UL   // 1,024
#define CSR_OFF      27866560UL   // 3,200,000
// total ≈ 31.1 MB

typedef __attribute__((ext_vector_type(8))) short short8;
typedef __attribute__((ext_vector_type(4))) float f32x4;

__device__ __forceinline__ unsigned short f2bf(float f) {
  unsigned int u = __float_as_uint(f);
  unsigned int r = (u + 0x7fffu + ((u >> 16) & 1u)) >> 16;
  return (unsigned short)r;
}
__device__ __forceinline__ float bf2f_lo(unsigned int u) {
  return __uint_as_float(u << 16);
}
__device__ __forceinline__ float bf2f_hi(unsigned int u) {
  return __uint_as_float(u & 0xffff0000u);
}

// ---------------- W swizzle: B-frag order for mfma_16x16x32_bf16 ----------------
// frag id = (t*4+kc)*64 + lane; element j of frag = W[kc*32+(lane>>4)*8+j][t*16+(lane&15)]
__global__ __launch_bounds__(256) void swizzle_W(const float* __restrict__ W,
                                                 unsigned short* __restrict__ Wsw) {
  int idx = blockIdx.x * 256 + threadIdx.x;  // 0..4095
  if (idx >= 4096) return;
  int l = idx & 63;
  int kc = (idx >> 6) & 3;
  int t = idx >> 8;
  int kbase = kc * 32 + (l >> 4) * 8;
  int col = t * 16 + (l & 15);
  unsigned int p[4];
#pragma unroll
  for (int j = 0; j < 4; ++j) {
    unsigned int lo = f2bf(W[(size_t)(kbase + 2 * j) * HC + col]);
    unsigned int hi = f2bf(W[(size_t)(kbase + 2 * j + 1) * HC + col]);
    p[j] = lo | (hi << 16);
  }
  *(uint4*)(Wsw + (size_t)idx * 8) = make_uint4(p[0], p[1], p[2], p[3]);
}

// ---------------- MFMA GEMM + fused logits ----------------
// block = 4 waves; wave w handles rows [bx*64+16w, +16), full N=256.
__global__ __launch_bounds__(256) void gemm_mfma(const float* __restrict__ x,
                                                 const unsigned short* __restrict__ Wsw,
                                                 const float* __restrict__ att_s,
                                                 const float* __restrict__ att_d,
                                                 unsigned short* __restrict__ hb,
                                                 float* __restrict__ a_src,
                                                 float* __restrict__ a_dst) {
  __shared__ float Cs[4][16][256];  // 64 KB, XOR-swizzled columns
  const int wave = threadIdx.x >> 6;
  const int l = threadIdx.x & 63;
  const int q = l >> 4;   // quad 0..3
  const int m = l & 15;
  const int mrow = blockIdx.x * 64 + wave * 16 + m;
  const bool mvalid = mrow < N_NODES;
  const int rc = mvalid ? mrow : (N_NODES - 1);

  // A fragments: lane holds x[rc][kc*32 + q*8 .. +7] as bf16
  short8 a[4];
  const float* xr = x + (size_t)rc * IN_CH + q * 8;
#pragma unroll
  for (int kc = 0; kc < 4; ++kc) {
    float4 u = *(const float4*)(xr + kc * 32);
    float4 v = *(const float4*)(xr + kc * 32 + 4);
    short8 t;
    t[0] = (short)f2bf(u.x); t[1] = (short)f2bf(u.y);
    t[2] = (short)f2bf(u.z); t[3] = (short)f2bf(u.w);
    t[4] = (short)f2bf(v.x); t[5] = (short)f2bf(v.y);
    t[6] = (short)f2bf(v.z); t[7] = (short)f2bf(v.w);
    a[kc] = t;
  }

#pragma unroll
  for (int t = 0; t < 16; ++t) {
    f32x4 acc = {0.f, 0.f, 0.f, 0.f};
#pragma unroll
    for (int kc = 0; kc < 4; ++kc) {
      short8 b = *(const short8*)(Wsw + ((size_t)(t * 4 + kc) * 64 + l) * 8);
      acc = __builtin_amdgcn_mfma_f32_16x16x32_bf16(a[kc], b, acc, 0, 0, 0);
    }
    // C/D: col = t*16+m (lane&15), row = q*4+r
#pragma unroll
    for (int r = 0; r < 4; ++r) {
      int row = q * 4 + r;
      Cs[wave][row][(t * 16 + m) ^ (row << 2)] = acc[r];
    }
  }
  __syncthreads();

  // read-back: lane = (row m, head q); cols q*64 .. q*64+63
  float as = 0.f, ad = 0.f;
  unsigned short* hrow = hb + (size_t)mrow * HC + q * 64;
  const int sw = m << 2;
#pragma unroll
  for (int i = 0; i < 8; ++i) {
    int col0 = q * 64 + i * 8;
    float4 c1 = *(const float4*)&Cs[wave][m][(col0) ^ sw];
    float4 c2 = *(const float4*)&Cs[wave][m][(col0 + 4) ^ sw];
    float4 s1 = *(const float4*)(att_s + col0);
    float4 s2 = *(const float4*)(att_s + col0 + 4);
    float4 d1 = *(const float4*)(att_d + col0);
    float4 d2 = *(const float4*)(att_d + col0 + 4);
    as += c1.x * s1.x + c1.y * s1.y + c1.z * s1.z + c1.w * s1.w;
    as += c2.x * s2.x + c2.y * s2.y + c2.z * s2.z + c2.w * s2.w;
    ad += c1.x * d1.x + c1.y * d1.y + c1.z * d1.z + c1.w * d1.w;
    ad += c2.x * d2.x + c2.y * d2.y + c2.z * d2.z + c2.w * d2.w;
    if (mvalid) {
      uint4 p;
      p.x = (unsigned int)f2bf(c1.x) | ((unsigned int)f2bf(c1.y) << 16);
      p.y = (unsigned int)f2bf(c1.z) | ((unsigned int)f2bf(c1.w) << 16);
      p.z = (unsigned int)f2bf(c2.x) | ((unsigned int)f2bf(c2.y) << 16);
      p.w = (unsigned int)f2bf(c2.z) | ((unsigned int)f2bf(c2.w) << 16);
      *(uint4*)(hrow + i * 8) = p;
    }
  }
  if (mvalid) {
    a_src[mrow * HEADS + q] = as;
    a_dst[mrow * HEADS + q] = ad;
  }
}

// ---------------- CSR build ----------------
__global__ __launch_bounds__(256) void count_k(const int* __restrict__ dst,
                                               int* __restrict__ counts) {
  int e = blockIdx.x * 256 + threadIdx.x;
  if (e < N_EDGES) atomicAdd(&counts[dst[e]], 1);
}

__global__ __launch_bounds__(256) void scan1(const int* __restrict__ counts,
                                             int* __restrict__ offsets,
                                             int* __restrict__ bsums) {
  __shared__ int sd[256];
  const int base = blockIdx.x * 1024;
  const int t = threadIdx.x;
  int v[4];
  int tsum = 0;
#pragma unroll
  for (int k = 0; k < 4; ++k) {
    int i = base + t * 4 + k;
    v[k] = (i < N_NODES) ? counts[i] : 0;
    tsum += v[k];
  }
  sd[t] = tsum;
  __syncthreads();
  for (int off = 1; off < 256; off <<= 1) {
    int xval = (t >= off) ? sd[t - off] : 0;
    __syncthreads();
    sd[t] += xval;
    __syncthreads();
  }
  int excl = sd[t] - tsum;
  int run = excl;
#pragma unroll
  for (int k = 0; k < 4; ++k) {
    int i = base + t * 4 + k;
    if (i < N_NODES) offsets[i] = run;
    run += v[k];
  }
  if (t == 255) bsums[blockIdx.x] = sd[255];
}

__global__ void scan2(int* __restrict__ bsums, int nb) {
  if (threadIdx.x == 0 && blockIdx.x == 0) {
    int run = 0;
    for (int b = 0; b < nb; ++b) {
      int t = bsums[b];
      bsums[b] = run;
      run += t;
    }
  }
}

__global__ __launch_bounds__(256) void scan3(int* __restrict__ offsets,
                                             const int* __restrict__ bsums,
                                             int* __restrict__ cursor) {
  const int base = blockIdx.x * 1024;
  const int t = threadIdx.x;
  int add = bsums[blockIdx.x];
#pragma unroll
  for (int k = 0; k < 4; ++k) {
    int i = base + t * 4 + k;
    if (i < N_NODES) {
      int o = offsets[i] + add;
      offsets[i] = o;
      cursor[i] = o;
    }
  }
}

__global__ __launch_bounds__(256) void scatter_k(const int* __restrict__ src,
                                                 const int* __restrict__ dst,
                                                 int* __restrict__ cursor,
                                                 int* __restrict__ csr) {
  int e = blockIdx.x * 256 + threadIdx.x;
  if (e < N_EDGES) {
    int d = dst[e];
    int pos = atomicAdd(&cursor[d], 1);
    csr[pos] = src[e];
  }
}

// ---------------- segment softmax + aggregate ----------------
// wave per node. Lane l: group g=l>>5 (edge parity), q=l&31 covers channels
// 8q..8q+7 (head = q>>3). Two edges processed per iteration, 16 B gathers.
__global__ __launch_bounds__(256) void aggregate(const unsigned short* __restrict__ hb,
                                                 const float* __restrict__ a_src,
                                                 const float* __restrict__ a_dst,
                                                 const int* __restrict__ counts,
                                                 const int* __restrict__ offsets,
                                                 const int* __restrict__ csr,
                                                 const float* __restrict__ bias,
                                                 float* __restrict__ out) {
  const int node = blockIdx.x * 4 + (threadIdx.x >> 6);
  const int l = threadIdx.x & 63;
  const int g = l >> 5;
  const int q = l & 31;
  const int hd = q >> 3;
  const int c0 = q * 8;
  const int deg = counts[node];
  const int start = offsets[node];
  const float adst = a_dst[node * HEADS + hd];

  float e_self = a_src[node * HEADS + hd] + adst;
  e_self = e_self > 0.f ? e_self : NEG_SLOPE * e_self;

  // pass 1: per-head max. 16 lanes per head (8 per group x 2 groups), stride 16.
  float mx = e_self;
  for (int j = g * 8 + (q & 7); j < deg; j += 16) {
    int s = csr[start + j];
    float e = a_src[s * HEADS + hd] + adst;
    e = e > 0.f ? e : NEG_SLOPE * e;
    mx = fmaxf(mx, e);
  }
  mx = fmaxf(mx, __shfl_xor(mx, 1));
  mx = fmaxf(mx, __shfl_xor(mx, 2));
  mx = fmaxf(mx, __shfl_xor(mx, 4));
  mx = fmaxf(mx, __shfl_xor(mx, 32));

  // pass 2: group g takes edges j+g, step 2
  float denom = 0.f;
  float acc[8] = {0.f, 0.f, 0.f, 0.f, 0.f, 0.f, 0.f, 0.f};
#pragma unroll 2
  for (int j = 0; j + g < deg; j += 2) {
    int s = csr[start + j + g];
    float e = a_src[s * HEADS + hd] + adst;
    e = e > 0.f ? e : NEG_SLOPE * e;
    float ex = __expf(e - mx);
    denom += ex;
    uint4 hv = *(const uint4*)(hb + (size_t)s * HC + c0);
    acc[0] += bf2f_lo(hv.x) * ex;
    acc[1] += bf2f_hi(hv.x) * ex;
    acc[2] += bf2f_lo(hv.y) * ex;
    acc[3] += bf2f_hi(hv.y) * ex;
    acc[4] += bf2f_lo(hv.z) * ex;
    acc[5] += bf2f_hi(hv.z) * ex;
    acc[6] += bf2f_lo(hv.w) * ex;
    acc[7] += bf2f_hi(hv.w) * ex;
  }
  // combine the two groups
  denom += __shfl_xor(denom, 32);
#pragma unroll
  for (int k = 0; k < 8; ++k) acc[k] += __shfl_xor(acc[k], 32);

  // self-loop
  float ex_self = __expf(e_self - mx);
  denom += ex_self;
  uint4 hs = *(const uint4*)(hb + (size_t)node * HC + c0);
  acc[0] += bf2f_lo(hs.x) * ex_self;
  acc[1] += bf2f_hi(hs.x) * ex_self;
  acc[2] += bf2f_lo(hs.y) * ex_self;
  acc[3] += bf2f_hi(hs.y) * ex_self;
  acc[4] += bf2f_lo(hs.z) * ex_self;
  acc[5] += bf2f_hi(hs.z) * ex_self;
  acc[6] += bf2f_lo(hs.w) * ex_self;
  acc[7] += bf2f_hi(hs.w) * ex_self;

  if (g == 0) {
    float inv = 1.f / (denom + 1e-16f);
    float4 b1 = *(const float4*)(bias + c0);
    float4 b2 = *(const float4*)(bias + c0 + 4);
    float4 o1 = make_float4(acc[0] * inv + b1.x, acc[1] * inv + b1.y,
                            acc[2] * inv + b1.z, acc[3] * inv + b1.w);
    float4 o2 = make_float4(acc[4] * inv + b2.x, acc[5] * inv + b2.y,
                            acc[6] * inv + b2.z, acc[7] * inv + b2.w);
    *(float4*)(out + (size_t)node * HC + c0) = o1;
    *(float4*)(out + (size_t)node * HC + c0 + 4) = o2;
  }
}

extern "C" void kernel_launch(void* const* d_in, const int* in_sizes, int n_in,
                              void* d_out, int out_size, void* d_ws, size_t ws_size,
                              hipStream_t stream) {
  const float* x     = (const float*)d_in[0];
  const int*   ei    = (const int*)d_in[1];
  const float* W     = (const float*)d_in[2];
  const float* att_s = (const float*)d_in[3];
  const float* att_d = (const float*)d_in[4];
  const float* bias  = (const float*)d_in[5];
  float* out = (float*)d_out;

  char* ws = (char*)d_ws;
  unsigned short* hb  = (unsigned short*)(ws + HB_OFF);
  unsigned short* Wsw = (unsigned short*)(ws + WSW_OFF);
  float* a_src  = (float*)(ws + ASRC_OFF);
  float* a_dst  = (float*)(ws + ADST_OFF);
  int* counts   = (int*)(ws + COUNTS_OFF);
  int* offsets  = (int*)(ws + OFFSETS_OFF);
  int* cursor   = (int*)(ws + CURSOR_OFF);
  int* bsums    = (int*)(ws + BSUMS_OFF);
  int* csr      = (int*)(ws + CSR_OFF);

  const int* src = ei;             // edge_index[0]
  const int* dst = ei + N_EDGES;   // edge_index[1]

  hipMemsetAsync(counts, 0, N_NODES * sizeof(int), stream);

  swizzle_W<<<16, 256, 0, stream>>>(W, Wsw);
  gemm_mfma<<<782, 256, 0, stream>>>(x, Wsw, att_s, att_d, hb, a_src, a_dst);
  count_k<<<3125, 256, 0, stream>>>(dst, counts);
  scan1<<<49, 256, 0, stream>>>(counts, offsets, bsums);
  scan2<<<1, 64, 0, stream>>>(bsums, 49);
  scan3<<<49, 256, 0, stream>>>(offsets, bsums, cursor);
  scatter_k<<<3125, 256, 0, stream>>>(src, dst, cursor, csr);
  aggregate<<<12500, 256, 0, stream>>>(hb, a_src, a_dst, counts, offsets, csr, bias, out);
}

// Round 4
// 263.572 us; speedup vs baseline: 1.5283x; 1.0332x over previous
//
#include <hip/hip_runtime.h>

#define N_NODES 50000
#define N_EDGES 800000
#define IN_CH 128
#define OUT_CH 64
#define HEADS 4
#define HC 256  // HEADS*OUT_CH
#define NEG_SLOPE 0.2f
#define GEMM_BLOCKS 782   // ceil(50000/64)
#define COUNT_BLOCKS 782  // ceil(800000/1024)

// ---------------- workspace layout (bytes) ----------------
#define HB_OFF       0UL          // bf16 h: 25,600,000
#define WSW_OFF      25600000UL   // swizzled bf16 W: 65,536
#define ASRC_OFF     25665536UL   // float4/node: 800,000
#define ADST_OFF     26465536UL   // 800,000
#define COUNTS_OFF   27265536UL   // 200,000
#define OFFSETS_OFF  27465536UL   // 200,000
#define CURSOR_OFF   27665536UL   // 200,000
#define BSUMS_OFF    27865536UL   // 1,024
#define CSR_OFF      27866560UL   // 3,200,000
#define EXV_OFF      31066560UL   // float4/edge: 12,800,000  (16B aligned)
// total ≈ 43.9 MB

typedef __attribute__((ext_vector_type(8))) short short8;
typedef __attribute__((ext_vector_type(4))) float f32x4;

__device__ __forceinline__ unsigned short f2bf(float f) {
  unsigned int u = __float_as_uint(f);
  unsigned int r = (u + 0x7fffu + ((u >> 16) & 1u)) >> 16;
  return (unsigned short)r;
}
__device__ __forceinline__ float bf2f_lo(unsigned int u) {
  return __uint_as_float(u << 16);
}
__device__ __forceinline__ float bf2f_hi(unsigned int u) {
  return __uint_as_float(u & 0xffff0000u);
}
__device__ __forceinline__ float lrelu(float e) {
  return e > 0.f ? e : NEG_SLOPE * e;
}

// ---------------- W swizzle: B-frag order for mfma_16x16x32_bf16 ----------------
__global__ __launch_bounds__(256) void swizzle_W(const float* __restrict__ W,
                                                 unsigned short* __restrict__ Wsw) {
  int idx = blockIdx.x * 256 + threadIdx.x;  // 0..4095
  if (idx >= 4096) return;
  int l = idx & 63;
  int kc = (idx >> 6) & 3;
  int t = idx >> 8;
  int kbase = kc * 32 + (l >> 4) * 8;
  int col = t * 16 + (l & 15);
  unsigned int p[4];
#pragma unroll
  for (int j = 0; j < 4; ++j) {
    unsigned int lo = f2bf(W[(size_t)(kbase + 2 * j) * HC + col]);
    unsigned int hi = f2bf(W[(size_t)(kbase + 2 * j + 1) * HC + col]);
    p[j] = lo | (hi << 16);
  }
  *(uint4*)(Wsw + (size_t)idx * 8) = make_uint4(p[0], p[1], p[2], p[3]);
}

// ---------------- MFMA GEMM + fused logits, with count_k piggybacked ----------------
__global__ __launch_bounds__(256) void gemm_count(const float* __restrict__ x,
                                                  const unsigned short* __restrict__ Wsw,
                                                  const float* __restrict__ att_s,
                                                  const float* __restrict__ att_d,
                                                  const int* __restrict__ dstv,
                                                  unsigned short* __restrict__ hb,
                                                  float* __restrict__ a_src,
                                                  float* __restrict__ a_dst,
                                                  int* __restrict__ counts) {
  __shared__ float Cs[4][16][256];  // 64 KB, XOR-swizzled columns

  if (blockIdx.x >= GEMM_BLOCKS) {  // ---- count role ----
    int base = (blockIdx.x - GEMM_BLOCKS) * 1024 + threadIdx.x;
#pragma unroll
    for (int k = 0; k < 4; ++k) {
      int e = base + k * 256;
      if (e < N_EDGES) atomicAdd(&counts[dstv[e]], 1);
    }
    return;
  }

  const int wave = threadIdx.x >> 6;
  const int l = threadIdx.x & 63;
  const int q = l >> 4;
  const int m = l & 15;
  const int mrow = blockIdx.x * 64 + wave * 16 + m;
  const bool mvalid = mrow < N_NODES;
  const int rc = mvalid ? mrow : (N_NODES - 1);

  short8 a[4];
  const float* xr = x + (size_t)rc * IN_CH + q * 8;
#pragma unroll
  for (int kc = 0; kc < 4; ++kc) {
    float4 u = *(const float4*)(xr + kc * 32);
    float4 v = *(const float4*)(xr + kc * 32 + 4);
    short8 t;
    t[0] = (short)f2bf(u.x); t[1] = (short)f2bf(u.y);
    t[2] = (short)f2bf(u.z); t[3] = (short)f2bf(u.w);
    t[4] = (short)f2bf(v.x); t[5] = (short)f2bf(v.y);
    t[6] = (short)f2bf(v.z); t[7] = (short)f2bf(v.w);
    a[kc] = t;
  }

#pragma unroll
  for (int t = 0; t < 16; ++t) {
    f32x4 acc = {0.f, 0.f, 0.f, 0.f};
#pragma unroll
    for (int kc = 0; kc < 4; ++kc) {
      short8 b = *(const short8*)(Wsw + ((size_t)(t * 4 + kc) * 64 + l) * 8);
      acc = __builtin_amdgcn_mfma_f32_16x16x32_bf16(a[kc], b, acc, 0, 0, 0);
    }
#pragma unroll
    for (int r = 0; r < 4; ++r) {
      int row = q * 4 + r;
      Cs[wave][row][(t * 16 + m) ^ (row << 2)] = acc[r];
    }
  }
  __syncthreads();

  // read-back: lane = (row m, head q); cols q*64 .. q*64+63
  float as = 0.f, ad = 0.f;
  unsigned short* hrow = hb + (size_t)mrow * HC + q * 64;
  const int sw = m << 2;
#pragma unroll
  for (int i = 0; i < 8; ++i) {
    int col0 = q * 64 + i * 8;
    float4 c1 = *(const float4*)&Cs[wave][m][(col0) ^ sw];
    float4 c2 = *(const float4*)&Cs[wave][m][(col0 + 4) ^ sw];
    float4 s1 = *(const float4*)(att_s + col0);
    float4 s2 = *(const float4*)(att_s + col0 + 4);
    float4 d1 = *(const float4*)(att_d + col0);
    float4 d2 = *(const float4*)(att_d + col0 + 4);
    as += c1.x * s1.x + c1.y * s1.y + c1.z * s1.z + c1.w * s1.w;
    as += c2.x * s2.x + c2.y * s2.y + c2.z * s2.z + c2.w * s2.w;
    ad += c1.x * d1.x + c1.y * d1.y + c1.z * d1.z + c1.w * d1.w;
    ad += c2.x * d2.x + c2.y * d2.y + c2.z * d2.z + c2.w * d2.w;
    if (mvalid) {
      uint4 p;
      p.x = (unsigned int)f2bf(c1.x) | ((unsigned int)f2bf(c1.y) << 16);
      p.y = (unsigned int)f2bf(c1.z) | ((unsigned int)f2bf(c1.w) << 16);
      p.z = (unsigned int)f2bf(c2.x) | ((unsigned int)f2bf(c2.y) << 16);
      p.w = (unsigned int)f2bf(c2.z) | ((unsigned int)f2bf(c2.w) << 16);
      *(uint4*)(hrow + i * 8) = p;
    }
  }
  if (mvalid) {
    a_src[mrow * HEADS + q] = as;
    a_dst[mrow * HEADS + q] = ad;
  }
}

// ---------------- scan ----------------
__global__ __launch_bounds__(256) void scan1(const int* __restrict__ counts,
                                             int* __restrict__ offsets,
                                             int* __restrict__ bsums) {
  __shared__ int sd[256];
  const int base = blockIdx.x * 1024;
  const int t = threadIdx.x;
  int v[4];
  int tsum = 0;
#pragma unroll
  for (int k = 0; k < 4; ++k) {
    int i = base + t * 4 + k;
    v[k] = (i < N_NODES) ? counts[i] : 0;
    tsum += v[k];
  }
  sd[t] = tsum;
  __syncthreads();
  for (int off = 1; off < 256; off <<= 1) {
    int xval = (t >= off) ? sd[t - off] : 0;
    __syncthreads();
    sd[t] += xval;
    __syncthreads();
  }
  int excl = sd[t] - tsum;
  int run = excl;
#pragma unroll
  for (int k = 0; k < 4; ++k) {
    int i = base + t * 4 + k;
    if (i < N_NODES) offsets[i] = run;
    run += v[k];
  }
  if (t == 255) bsums[blockIdx.x] = sd[255];
}

__global__ void scan2(int* __restrict__ bsums, int nb) {
  if (threadIdx.x == 0 && blockIdx.x == 0) {
    int run = 0;
    for (int b = 0; b < nb; ++b) {
      int t = bsums[b];
      bsums[b] = run;
      run += t;
    }
  }
}

__global__ __launch_bounds__(256) void scan3(int* __restrict__ offsets,
                                             const int* __restrict__ bsums,
                                             int* __restrict__ cursor) {
  const int base = blockIdx.x * 1024;
  const int t = threadIdx.x;
  int add = bsums[blockIdx.x];
#pragma unroll
  for (int k = 0; k < 4; ++k) {
    int i = base + t * 4 + k;
    if (i < N_NODES) {
      int o = offsets[i] + add;
      offsets[i] = o;
      cursor[i] = o;
    }
  }
}

// ---------------- scatter + per-edge exp (all 4 heads) ----------------
__global__ __launch_bounds__(256) void scatter_k(const int* __restrict__ src,
                                                 const int* __restrict__ dst,
                                                 const float* __restrict__ a_src,
                                                 const float* __restrict__ a_dst,
                                                 int* __restrict__ cursor,
                                                 int* __restrict__ csr,
                                                 float* __restrict__ exv) {
  int e = blockIdx.x * 256 + threadIdx.x;
  if (e < N_EDGES) {
    int s = src[e];
    int d = dst[e];
    float4 as = *(const float4*)(a_src + s * 4);
    float4 ad = *(const float4*)(a_dst + d * 4);
    float4 ex;
    ex.x = __expf(lrelu(as.x + ad.x));
    ex.y = __expf(lrelu(as.y + ad.y));
    ex.z = __expf(lrelu(as.z + ad.z));
    ex.w = __expf(lrelu(as.w + ad.w));
    int pos = atomicAdd(&cursor[d], 1);
    csr[pos] = s;
    *(float4*)(exv + (size_t)pos * 4) = ex;
  }
}

// ---------------- aggregate: no max pass, precomputed exp ----------------
// wave per node. g=l>>5 (edge parity); q=l&31 covers channels 8q..8q+7.
__global__ __launch_bounds__(256) void aggregate(const unsigned short* __restrict__ hb,
                                                 const float* __restrict__ a_src,
                                                 const float* __restrict__ a_dst,
                                                 const int* __restrict__ counts,
                                                 const int* __restrict__ offsets,
                                                 const int* __restrict__ csr,
                                                 const float* __restrict__ exv,
                                                 const float* __restrict__ bias,
                                                 float* __restrict__ out) {
  const int node = blockIdx.x * 4 + (threadIdx.x >> 6);
  const int l = threadIdx.x & 63;
  const int g = l >> 5;
  const int q = l & 31;
  const int hd = q >> 3;
  const int c0 = q * 8;
  const int deg = counts[node];
  const int start = offsets[node];

  float denom = 0.f;
  float acc[8] = {0.f, 0.f, 0.f, 0.f, 0.f, 0.f, 0.f, 0.f};
#pragma unroll 2
  for (int j = 0; j + g < deg; j += 2) {
    int idx = start + j + g;
    int s = csr[idx];
    float ex = exv[(size_t)idx * 4 + hd];
    uint4 hv = *(const uint4*)(hb + (size_t)s * HC + c0);
    denom += ex;
    acc[0] += bf2f_lo(hv.x) * ex;
    acc[1] += bf2f_hi(hv.x) * ex;
    acc[2] += bf2f_lo(hv.y) * ex;
    acc[3] += bf2f_hi(hv.y) * ex;
    acc[4] += bf2f_lo(hv.z) * ex;
    acc[5] += bf2f_hi(hv.z) * ex;
    acc[6] += bf2f_lo(hv.w) * ex;
    acc[7] += bf2f_hi(hv.w) * ex;
  }
  // combine the two edge-parity groups
  denom += __shfl_xor(denom, 32);
#pragma unroll
  for (int k = 0; k < 8; ++k) acc[k] += __shfl_xor(acc[k], 32);

  // self-loop (added once, after combine)
  float es = a_src[node * HEADS + hd] + a_dst[node * HEADS + hd];
  float ex_self = __expf(lrelu(es));
  denom += ex_self;
  uint4 hs = *(const uint4*)(hb + (size_t)node * HC + c0);
  acc[0] += bf2f_lo(hs.x) * ex_self;
  acc[1] += bf2f_hi(hs.x) * ex_self;
  acc[2] += bf2f_lo(hs.y) * ex_self;
  acc[3] += bf2f_hi(hs.y) * ex_self;
  acc[4] += bf2f_lo(hs.z) * ex_self;
  acc[5] += bf2f_hi(hs.z) * ex_self;
  acc[6] += bf2f_lo(hs.w) * ex_self;
  acc[7] += bf2f_hi(hs.w) * ex_self;

  if (g == 0) {
    float inv = 1.f / (denom + 1e-16f);
    float4 b1 = *(const float4*)(bias + c0);
    float4 b2 = *(const float4*)(bias + c0 + 4);
    float4 o1 = make_float4(acc[0] * inv + b1.x, acc[1] * inv + b1.y,
                            acc[2] * inv + b1.z, acc[3] * inv + b1.w);
    float4 o2 = make_float4(acc[4] * inv + b2.x, acc[5] * inv + b2.y,
                            acc[6] * inv + b2.z, acc[7] * inv + b2.w);
    *(float4*)(out + (size_t)node * HC + c0) = o1;
    *(float4*)(out + (size_t)node * HC + c0 + 4) = o2;
  }
}

extern "C" void kernel_launch(void* const* d_in, const int* in_sizes, int n_in,
                              void* d_out, int out_size, void* d_ws, size_t ws_size,
                              hipStream_t stream) {
  const float* x     = (const float*)d_in[0];
  const int*   ei    = (const int*)d_in[1];
  const float* W     = (const float*)d_in[2];
  const float* att_s = (const float*)d_in[3];
  const float* att_d = (const float*)d_in[4];
  const float* bias  = (const float*)d_in[5];
  float* out = (float*)d_out;

  char* ws = (char*)d_ws;
  unsigned short* hb  = (unsigned short*)(ws + HB_OFF);
  unsigned short* Wsw = (unsigned short*)(ws + WSW_OFF);
  float* a_src  = (float*)(ws + ASRC_OFF);
  float* a_dst  = (float*)(ws + ADST_OFF);
  int* counts   = (int*)(ws + COUNTS_OFF);
  int* offsets  = (int*)(ws + OFFSETS_OFF);
  int* cursor   = (int*)(ws + CURSOR_OFF);
  int* bsums    = (int*)(ws + BSUMS_OFF);
  int* csr      = (int*)(ws + CSR_OFF);
  float* exv    = (float*)(ws + EXV_OFF);

  const int* src = ei;             // edge_index[0]
  const int* dst = ei + N_EDGES;   // edge_index[1]

  hipMemsetAsync(counts, 0, N_NODES * sizeof(int), stream);

  swizzle_W<<<16, 256, 0, stream>>>(W, Wsw);
  gemm_count<<<GEMM_BLOCKS + COUNT_BLOCKS, 256, 0, stream>>>(
      x, Wsw, att_s, att_d, dst, hb, a_src, a_dst, counts);
  scan1<<<49, 256, 0, stream>>>(counts, offsets, bsums);
  scan2<<<1, 64, 0, stream>>>(bsums, 49);
  scan3<<<49, 256, 0, stream>>>(offsets, bsums, cursor);
  scatter_k<<<3125, 256, 0, stream>>>(src, dst, a_src, a_dst, cursor, csr, exv);
  aggregate<<<12500, 256, 0, stream>>>(hb, a_src, a_dst, counts, offsets, csr, exv, bias, out);
}

// Round 5
// 248.722 us; speedup vs baseline: 1.6195x; 1.0597x over previous
//
#include <hip/hip_runtime.h>

#define N_NODES 50000
#define N_EDGES 800000
#define IN_CH 128
#define OUT_CH 64
#define HEADS 4
#define HC 256  // HEADS*OUT_CH
#define NEG_SLOPE 0.2f
#define GEMM_BLOCKS 782    // ceil(50000/64)
#define COUNT_BLOCKS 782   // ceil(800000/1024)
#define SCAN_BLOCKS 49     // ceil(50000/1024)

// ---------------- workspace layout (bytes) ----------------
#define HB_OFF       0UL          // bf16 h: 25,600,000
#define WSW_OFF      25600000UL   // swizzled bf16 W: 65,536
#define ASRC_OFF     25665536UL   // 800,000
#define ADST_OFF     26465536UL   // 800,000
#define COUNTS_OFF   27265536UL   // 200,000
#define OFFSETS_OFF  27465536UL   // 200,000
#define CURSOR_OFF   27665536UL   // 200,000
#define BSUMS_OFF    27865536UL   // 1,024
#define REC_OFF      27866560UL   // 32B/edge: 25,600,000
// total ≈ 53.5 MB (R1 used 56.6 MB OK)

typedef __attribute__((ext_vector_type(8))) short short8;
typedef __attribute__((ext_vector_type(4))) float f32x4;

__device__ __forceinline__ unsigned short f2bf(float f) {
  unsigned int u = __float_as_uint(f);
  unsigned int r = (u + 0x7fffu + ((u >> 16) & 1u)) >> 16;
  return (unsigned short)r;
}
__device__ __forceinline__ float bf2f_lo(unsigned int u) {
  return __uint_as_float(u << 16);
}
__device__ __forceinline__ float bf2f_hi(unsigned int u) {
  return __uint_as_float(u & 0xffff0000u);
}
__device__ __forceinline__ float lrelu(float e) {
  return e > 0.f ? e : NEG_SLOPE * e;
}

// ---------------- init: W swizzle (blocks 0-15) + counts zero (blocks 16+) ----------------
__global__ __launch_bounds__(256) void init_k(const float* __restrict__ W,
                                              unsigned short* __restrict__ Wsw,
                                              int* __restrict__ counts) {
  if (blockIdx.x < 16) {
    int idx = blockIdx.x * 256 + threadIdx.x;  // 0..4095
    int l = idx & 63;
    int kc = (idx >> 6) & 3;
    int t = idx >> 8;
    int kbase = kc * 32 + (l >> 4) * 8;
    int col = t * 16 + (l & 15);
    unsigned int p[4];
#pragma unroll
    for (int j = 0; j < 4; ++j) {
      unsigned int lo = f2bf(W[(size_t)(kbase + 2 * j) * HC + col]);
      unsigned int hi = f2bf(W[(size_t)(kbase + 2 * j + 1) * HC + col]);
      p[j] = lo | (hi << 16);
    }
    *(uint4*)(Wsw + (size_t)idx * 8) = make_uint4(p[0], p[1], p[2], p[3]);
  } else {
    int i = (blockIdx.x - 16) * 256 + threadIdx.x;
    if (i < N_NODES) counts[i] = 0;
  }
}

// ---------------- MFMA GEMM + fused logits, count_k piggybacked ----------------
__global__ __launch_bounds__(256) void gemm_count(const float* __restrict__ x,
                                                  const unsigned short* __restrict__ Wsw,
                                                  const float* __restrict__ att_s,
                                                  const float* __restrict__ att_d,
                                                  const int* __restrict__ dstv,
                                                  unsigned short* __restrict__ hb,
                                                  float* __restrict__ a_src,
                                                  float* __restrict__ a_dst,
                                                  int* __restrict__ counts) {
  __shared__ float Cs[4][16][256];  // 64 KB, XOR-swizzled columns

  if (blockIdx.x >= GEMM_BLOCKS) {  // ---- count role ----
    int base = (blockIdx.x - GEMM_BLOCKS) * 1024 + threadIdx.x;
#pragma unroll
    for (int k = 0; k < 4; ++k) {
      int e = base + k * 256;
      if (e < N_EDGES) atomicAdd(&counts[dstv[e]], 1);
    }
    return;
  }

  const int wave = threadIdx.x >> 6;
  const int l = threadIdx.x & 63;
  const int q = l >> 4;
  const int m = l & 15;
  const int mrow = blockIdx.x * 64 + wave * 16 + m;
  const bool mvalid = mrow < N_NODES;
  const int rc = mvalid ? mrow : (N_NODES - 1);

  short8 a[4];
  const float* xr = x + (size_t)rc * IN_CH + q * 8;
#pragma unroll
  for (int kc = 0; kc < 4; ++kc) {
    float4 u = *(const float4*)(xr + kc * 32);
    float4 v = *(const float4*)(xr + kc * 32 + 4);
    short8 t;
    t[0] = (short)f2bf(u.x); t[1] = (short)f2bf(u.y);
    t[2] = (short)f2bf(u.z); t[3] = (short)f2bf(u.w);
    t[4] = (short)f2bf(v.x); t[5] = (short)f2bf(v.y);
    t[6] = (short)f2bf(v.z); t[7] = (short)f2bf(v.w);
    a[kc] = t;
  }

#pragma unroll
  for (int t = 0; t < 16; ++t) {
    f32x4 acc = {0.f, 0.f, 0.f, 0.f};
#pragma unroll
    for (int kc = 0; kc < 4; ++kc) {
      short8 b = *(const short8*)(Wsw + ((size_t)(t * 4 + kc) * 64 + l) * 8);
      acc = __builtin_amdgcn_mfma_f32_16x16x32_bf16(a[kc], b, acc, 0, 0, 0);
    }
#pragma unroll
    for (int r = 0; r < 4; ++r) {
      int row = q * 4 + r;
      Cs[wave][row][(t * 16 + m) ^ (row << 2)] = acc[r];
    }
  }
  __syncthreads();

  // read-back: lane = (row m, head q); cols q*64 .. q*64+63
  float as = 0.f, ad = 0.f;
  unsigned short* hrow = hb + (size_t)mrow * HC + q * 64;
  const int sw = m << 2;
#pragma unroll
  for (int i = 0; i < 8; ++i) {
    int col0 = q * 64 + i * 8;
    float4 c1 = *(const float4*)&Cs[wave][m][(col0) ^ sw];
    float4 c2 = *(const float4*)&Cs[wave][m][(col0 + 4) ^ sw];
    float4 s1 = *(const float4*)(att_s + col0);
    float4 s2 = *(const float4*)(att_s + col0 + 4);
    float4 d1 = *(const float4*)(att_d + col0);
    float4 d2 = *(const float4*)(att_d + col0 + 4);
    as += c1.x * s1.x + c1.y * s1.y + c1.z * s1.z + c1.w * s1.w;
    as += c2.x * s2.x + c2.y * s2.y + c2.z * s2.z + c2.w * s2.w;
    ad += c1.x * d1.x + c1.y * d1.y + c1.z * d1.z + c1.w * d1.w;
    ad += c2.x * d2.x + c2.y * d2.y + c2.z * d2.z + c2.w * d2.w;
    if (mvalid) {
      uint4 p;
      p.x = (unsigned int)f2bf(c1.x) | ((unsigned int)f2bf(c1.y) << 16);
      p.y = (unsigned int)f2bf(c1.z) | ((unsigned int)f2bf(c1.w) << 16);
      p.z = (unsigned int)f2bf(c2.x) | ((unsigned int)f2bf(c2.y) << 16);
      p.w = (unsigned int)f2bf(c2.z) | ((unsigned int)f2bf(c2.w) << 16);
      *(uint4*)(hrow + i * 8) = p;
    }
  }
  if (mvalid) {
    a_src[mrow * HEADS + q] = as;
    a_dst[mrow * HEADS + q] = ad;
  }
}

// ---------------- scan ----------------
__global__ __launch_bounds__(256) void scan1(const int* __restrict__ counts,
                                             int* __restrict__ offsets,
                                             int* __restrict__ bsums) {
  __shared__ int sd[256];
  const int base = blockIdx.x * 1024;
  const int t = threadIdx.x;
  int v[4];
  int tsum = 0;
#pragma unroll
  for (int k = 0; k < 4; ++k) {
    int i = base + t * 4 + k;
    v[k] = (i < N_NODES) ? counts[i] : 0;
    tsum += v[k];
  }
  sd[t] = tsum;
  __syncthreads();
  for (int off = 1; off < 256; off <<= 1) {
    int xval = (t >= off) ? sd[t - off] : 0;
    __syncthreads();
    sd[t] += xval;
    __syncthreads();
  }
  int excl = sd[t] - tsum;
  int run = excl;
#pragma unroll
  for (int k = 0; k < 4; ++k) {
    int i = base + t * 4 + k;
    if (i < N_NODES) offsets[i] = run;
    run += v[k];
  }
  if (t == 255) bsums[blockIdx.x] = sd[255];
}

// scan2+scan3 fused: every block redundantly wave-scans the 49 block sums.
__global__ __launch_bounds__(256) void scan23(int* __restrict__ offsets,
                                              const int* __restrict__ bsums,
                                              int* __restrict__ cursor) {
  __shared__ int s_add;
  if (threadIdx.x < 64) {
    int lane = threadIdx.x;
    int v = (lane < SCAN_BLOCKS) ? bsums[lane] : 0;
#pragma unroll
    for (int o = 1; o < 64; o <<= 1) {
      int t = __shfl_up(v, o);
      if (lane >= o) v += t;
    }
    int b = blockIdx.x;
    int pre = (b == 0) ? 0 : __shfl(v, b - 1);
    if (lane == 0) s_add = pre;
  }
  __syncthreads();
  const int add = s_add;
  const int base = blockIdx.x * 1024;
  const int t = threadIdx.x;
#pragma unroll
  for (int k = 0; k < 4; ++k) {
    int i = base + t * 4 + k;
    if (i < N_NODES) {
      int o = offsets[i] + add;
      offsets[i] = o;
      cursor[i] = o;
    }
  }
}

// ---------------- scatter: one 32B record {src, ex4} per edge ----------------
__global__ __launch_bounds__(256) void scatter_k(const int* __restrict__ src,
                                                 const int* __restrict__ dst,
                                                 const float* __restrict__ a_src,
                                                 const float* __restrict__ a_dst,
                                                 int* __restrict__ cursor,
                                                 char* __restrict__ rec) {
  int e = blockIdx.x * 256 + threadIdx.x;
  if (e < N_EDGES) {
    int s = src[e];
    int d = dst[e];
    float4 as = *(const float4*)(a_src + s * 4);
    float4 ad = *(const float4*)(a_dst + d * 4);
    float4 ex;
    ex.x = __expf(lrelu(as.x + ad.x));
    ex.y = __expf(lrelu(as.y + ad.y));
    ex.z = __expf(lrelu(as.z + ad.z));
    ex.w = __expf(lrelu(as.w + ad.w));
    int pos = atomicAdd(&cursor[d], 1);
    char* rp = rec + (size_t)pos * 32;
    *(uint4*)rp = make_uint4((unsigned)s, __float_as_uint(ex.x),
                             __float_as_uint(ex.y), __float_as_uint(ex.z));
    *(unsigned*)(rp + 16) = __float_as_uint(ex.w);
  }
}

// ---------------- aggregate: 4 edge groups x 16 lanes, 32B/lane ----------------
__global__ __launch_bounds__(256) void aggregate(const unsigned short* __restrict__ hb,
                                                 const float* __restrict__ a_src,
                                                 const float* __restrict__ a_dst,
                                                 const int* __restrict__ counts,
                                                 const int* __restrict__ offsets,
                                                 const char* __restrict__ rec,
                                                 const float* __restrict__ bias,
                                                 float* __restrict__ out) {
  const int node = blockIdx.x * 4 + (threadIdx.x >> 6);
  const int l = threadIdx.x & 63;
  const int g = l >> 4;   // edge-parity group 0..3
  const int q = l & 15;   // channel slice: 16 channels at c0=q*16
  const int hd = q >> 2;
  const int cb = q * 32;  // byte offset into 512B row
  const int deg = counts[node];
  const int start = offsets[node];
  const char* hbase = (const char*)hb;

  float denom = 0.f;
  float acc[16];
#pragma unroll
  for (int k = 0; k < 16; ++k) acc[k] = 0.f;

#pragma unroll 2
  for (int j = 0; j + g < deg; j += 4) {
    int idx = start + j + g;
    const char* rp = rec + (size_t)idx * 32;
    int s = *(const int*)rp;
    float ex = *(const float*)(rp + 4 + hd * 4);
    const char* hp = hbase + (size_t)s * 512 + cb;
    uint4 h0 = *(const uint4*)hp;
    uint4 h1 = *(const uint4*)(hp + 16);
    denom += ex;
    acc[0] += bf2f_lo(h0.x) * ex;  acc[1] += bf2f_hi(h0.x) * ex;
    acc[2] += bf2f_lo(h0.y) * ex;  acc[3] += bf2f_hi(h0.y) * ex;
    acc[4] += bf2f_lo(h0.z) * ex;  acc[5] += bf2f_hi(h0.z) * ex;
    acc[6] += bf2f_lo(h0.w) * ex;  acc[7] += bf2f_hi(h0.w) * ex;
    acc[8] += bf2f_lo(h1.x) * ex;  acc[9] += bf2f_hi(h1.x) * ex;
    acc[10] += bf2f_lo(h1.y) * ex; acc[11] += bf2f_hi(h1.y) * ex;
    acc[12] += bf2f_lo(h1.z) * ex; acc[13] += bf2f_hi(h1.z) * ex;
    acc[14] += bf2f_lo(h1.w) * ex; acc[15] += bf2f_hi(h1.w) * ex;
  }

  // combine the 4 edge groups
  denom += __shfl_xor(denom, 16);
  denom += __shfl_xor(denom, 32);
#pragma unroll
  for (int k = 0; k < 16; ++k) {
    acc[k] += __shfl_xor(acc[k], 16);
    acc[k] += __shfl_xor(acc[k], 32);
  }

  // self-loop (identical across groups; added once per lane)
  float es = a_src[node * HEADS + hd] + a_dst[node * HEADS + hd];
  float exs = __expf(lrelu(es));
  denom += exs;
  const char* hp = hbase + (size_t)node * 512 + cb;
  uint4 h0 = *(const uint4*)hp;
  uint4 h1 = *(const uint4*)(hp + 16);
  acc[0] += bf2f_lo(h0.x) * exs;  acc[1] += bf2f_hi(h0.x) * exs;
  acc[2] += bf2f_lo(h0.y) * exs;  acc[3] += bf2f_hi(h0.y) * exs;
  acc[4] += bf2f_lo(h0.z) * exs;  acc[5] += bf2f_hi(h0.z) * exs;
  acc[6] += bf2f_lo(h0.w) * exs;  acc[7] += bf2f_hi(h0.w) * exs;
  acc[8] += bf2f_lo(h1.x) * exs;  acc[9] += bf2f_hi(h1.x) * exs;
  acc[10] += bf2f_lo(h1.y) * exs; acc[11] += bf2f_hi(h1.y) * exs;
  acc[12] += bf2f_lo(h1.z) * exs; acc[13] += bf2f_hi(h1.z) * exs;
  acc[14] += bf2f_lo(h1.w) * exs; acc[15] += bf2f_hi(h1.w) * exs;

  float inv = 1.f / (denom + 1e-16f);
  // each group stores its own float4 slice: channels q*16 + g*4 .. +3
  int c = q * 16 + g * 4;
  float4 bv = *(const float4*)(bias + c);
  float4 o = make_float4(acc[g * 4 + 0] * inv + bv.x, acc[g * 4 + 1] * inv + bv.y,
                         acc[g * 4 + 2] * inv + bv.z, acc[g * 4 + 3] * inv + bv.w);
  *(float4*)(out + (size_t)node * HC + c) = o;
}

extern "C" void kernel_launch(void* const* d_in, const int* in_sizes, int n_in,
                              void* d_out, int out_size, void* d_ws, size_t ws_size,
                              hipStream_t stream) {
  const float* x     = (const float*)d_in[0];
  const int*   ei    = (const int*)d_in[1];
  const float* W     = (const float*)d_in[2];
  const float* att_s = (const float*)d_in[3];
  const float* att_d = (const float*)d_in[4];
  const float* bias  = (const float*)d_in[5];
  float* out = (float*)d_out;

  char* ws = (char*)d_ws;
  unsigned short* hb  = (unsigned short*)(ws + HB_OFF);
  unsigned short* Wsw = (unsigned short*)(ws + WSW_OFF);
  float* a_src  = (float*)(ws + ASRC_OFF);
  float* a_dst  = (float*)(ws + ADST_OFF);
  int* counts   = (int*)(ws + COUNTS_OFF);
  int* offsets  = (int*)(ws + OFFSETS_OFF);
  int* cursor   = (int*)(ws + CURSOR_OFF);
  int* bsums    = (int*)(ws + BSUMS_OFF);
  char* rec     = (char*)(ws + REC_OFF);

  const int* src = ei;             // edge_index[0]
  const int* dst = ei + N_EDGES;   // edge_index[1]

  init_k<<<16 + 196, 256, 0, stream>>>(W, Wsw, counts);
  gemm_count<<<GEMM_BLOCKS + COUNT_BLOCKS, 256, 0, stream>>>(
      x, Wsw, att_s, att_d, dst, hb, a_src, a_dst, counts);
  scan1<<<SCAN_BLOCKS, 256, 0, stream>>>(counts, offsets, bsums);
  scan23<<<SCAN_BLOCKS, 256, 0, stream>>>(offsets, bsums, cursor);
  scatter_k<<<3125, 256, 0, stream>>>(src, dst, a_src, a_dst, cursor, rec);
  aggregate<<<12500, 256, 0, stream>>>(hb, a_src, a_dst, counts, offsets, rec, bias, out);
}